// Round 1
// baseline (637.978 us; speedup 1.0000x reference)
//
#include <hip/hip_runtime.h>
#include <stdint.h>

#define B_ 4
#define N_ 16384
#define D_ 1024
#define RANK_ 16
#define NUMQ_ 8
#define KSEL_ 1638
#define NBIN0 2048   // 2^11 top-bits histogram bins per batch

typedef float floatx4 __attribute__((ext_vector_type(4)));

// ---------------- Kernel 1: Wq = queries @ Wk  -> [NUMQ, D]; also zero ghist ----------------
// NUMQ_*D_ == 8192 == B_*NBIN0, so the same threads zero the histogram.
__global__ __launch_bounds__(256) void wq_kernel(const float* __restrict__ Wk,
                                                 const float* __restrict__ queries,
                                                 float* __restrict__ Wq,
                                                 unsigned int* __restrict__ ghist) {
    int i = blockIdx.x * 256 + threadIdx.x;   // 0 .. NUMQ*D-1 (8192)
    if (i >= NUMQ_ * D_) return;
    ghist[i] = 0u;
    int q = i >> 10;          // / D_
    int d = i & (D_ - 1);     // % D_
    float acc = 0.f;
#pragma unroll
    for (int r = 0; r < RANK_; ++r)
        acc += queries[q * RANK_ + r] * Wk[r * D_ + d];
    Wq[i] = acc;
}

// ------------- Kernel 2: keys[t] = radix_key( max_q ( x[t,:] . Wq[q,:] ) ) -------------
// One wave processes TOK=4 tokens per iteration. Wq staged in LDS (32 KiB).
// Reduction: folding multi-value butterfly — 13 shuffles/token.
// Writes the order-preserving uint32 key directly and accumulates the
// per-batch top-11-bit histogram with one global atomic per token (hidden
// under the HBM-bound stream).
#define TOK 4

#define FOLD(dst, a, b, bit, dist)                          \
    {                                                       \
        float _send = (bit) ? (a) : (b);                    \
        float _recv = __shfl_xor(_send, (dist), 64);        \
        (dst) = ((bit) ? (b) : (a)) + _recv;                \
    }

__global__ __launch_bounds__(256) void score_kernel(const float* __restrict__ x,
                                                    const float* __restrict__ Wq,
                                                    unsigned int* __restrict__ keys,
                                                    unsigned int* __restrict__ ghist) {
    __shared__ float sWq[NUMQ_ * D_];   // 32 KiB
    for (int i = threadIdx.x; i < (NUMQ_ * D_) / 4; i += 256)
        ((float4*)sWq)[i] = ((const float4*)Wq)[i];
    __syncthreads();

    const int lane = threadIdx.x & 63;
    const int wave = threadIdx.x >> 6;
    const int gw = blockIdx.x * 4 + wave;
    const int numWaves = gridDim.x * 4;
    const int totalTok = B_ * N_;

    const int l5 = (lane >> 5) & 1;
    const int l4 = (lane >> 4) & 1;
    const int l3 = (lane >> 3) & 1;

    for (int t0 = gw * TOK; t0 < totalTok; t0 += numWaves * TOK) {
        float acc[TOK][NUMQ_];
#pragma unroll
        for (int t = 0; t < TOK; ++t)
#pragma unroll
            for (int q = 0; q < NUMQ_; ++q) acc[t][q] = 0.f;

#pragma unroll
        for (int j = 0; j < 4; ++j) {
            const int off = j * 256 + lane * 4;   // lane-coalesced float4
            floatx4 xv[TOK];
#pragma unroll
            for (int t = 0; t < TOK; ++t)
                xv[t] = __builtin_nontemporal_load(
                    (const floatx4*)(x + (size_t)(t0 + t) * D_ + off));
#pragma unroll
            for (int q = 0; q < NUMQ_; ++q) {
                floatx4 w = *(const floatx4*)(sWq + q * D_ + off);
#pragma unroll
                for (int t = 0; t < TOK; ++t) {
                    acc[t][q] += xv[t].x * w.x;
                    acc[t][q] += xv[t].y * w.y;
                    acc[t][q] += xv[t].z * w.z;
                    acc[t][q] += xv[t].w * w.w;
                }
            }
        }

        const int bIdx = t0 >> 14;   // batch (N_ = 2^14; TOK-aligned t0)
#pragma unroll
        for (int t = 0; t < TOK; ++t) {
            float n0, n1, n2, n3;
            FOLD(n0, acc[t][0], acc[t][4], l5, 32)
            FOLD(n1, acc[t][1], acc[t][5], l5, 32)
            FOLD(n2, acc[t][2], acc[t][6], l5, 32)
            FOLD(n3, acc[t][3], acc[t][7], l5, 32)
            float m0, m1;
            FOLD(m0, n0, n2, l4, 16)
            FOLD(m1, n1, n3, l4, 16)
            float p;
            FOLD(p, m0, m1, l3, 8)
            p += __shfl_xor(p, 4, 64);
            p += __shfl_xor(p, 2, 64);
            p += __shfl_xor(p, 1, 64);
            float mx = p;
            mx = fmaxf(mx, __shfl_xor(mx, 8, 64));
            mx = fmaxf(mx, __shfl_xor(mx, 16, 64));
            mx = fmaxf(mx, __shfl_xor(mx, 32, 64));
            if (lane == t) {
                unsigned int u = __float_as_uint(mx);
                u = (u & 0x80000000u) ? ~u : (u | 0x80000000u);
                keys[t0 + t] = u;
                atomicAdd(&ghist[bIdx * NBIN0 + (u >> 21)], 1u);
            }
        }
    }
}

// ------------- Kernel 3: per-batch top-K indices, sorted ascending -------------
// Radix-select 11/11/10 bits over precomputed uint32 keys. Pass-0 histogram is
// taken from ghist (built for free inside the HBM-bound score kernel), so only
// passes 1-2 scan the keys (predicate almost never true -> atomics rare).
// 1024 threads/block (16 waves); uint4-vectorized staging and scans.
__global__ __launch_bounds__(1024) void topk_kernel(const unsigned int* __restrict__ keys,
                                                    const unsigned int* __restrict__ ghist,
                                                    int* __restrict__ out) {
    __shared__ __align__(16) unsigned int sKeys[N_];   // 64 KiB
    __shared__ unsigned int hist[NBIN0];               // 8 KiB
    __shared__ unsigned int sSuf[1024];                // 4 KiB
    __shared__ unsigned int waveTot[16];
    __shared__ unsigned int wTotG[16];
    __shared__ int sTs;
    __shared__ unsigned int sPrefix, sR;

    const int b = blockIdx.x;
    const int tid = threadIdx.x;
    const int lane = tid & 63;
    const int wave = tid >> 6;

    // vectorized stage of pre-transformed keys + precomputed pass-0 histogram
    const uint4* kv = (const uint4*)(keys + b * N_);
    uint4* sk4 = (uint4*)sKeys;
    for (int i = tid; i < N_ / 4; i += 1024) sk4[i] = kv[i];
    for (int i = tid; i < NBIN0; i += 1024) hist[i] = ghist[b * NBIN0 + i];
    __syncthreads();

    unsigned int prefix = 0;
    unsigned int R = KSEL_;   // rank from the top within the current prefix class

    const int shifts[3] = {21, 10, 0};
    const int widths[3] = {11, 11, 10};

#pragma unroll 1
    for (int pass = 0; pass < 3; ++pass) {
        const int shift = shifts[pass];
        const unsigned int nb = 1u << widths[pass];
        const unsigned int binmask = nb - 1u;

        if (pass > 0) {   // pass 0 histogram arrives precomputed
            const unsigned int maskHi = 0xFFFFFFFFu << (shift + widths[pass]);
            for (int i = tid; i < (int)nb; i += 1024) hist[i] = 0;
            __syncthreads();
            for (int i = tid; i < N_ / 4; i += 1024) {
                uint4 u4 = sk4[i];
                unsigned int us[4] = {u4.x, u4.y, u4.z, u4.w};
#pragma unroll
                for (int c = 0; c < 4; ++c) {
                    unsigned int u = us[c];
                    if ((u & maskHi) == prefix)
                        atomicAdd(&hist[(u >> shift) & binmask], 1u);
                }
            }
            __syncthreads();
        }

        // per-thread segment sum (seg consecutive bins), then suffix scan
        const int seg = (int)(nb >> 10);           // nb/1024: 2,2,1
        unsigned int v = 0;
        for (int j = 0; j < seg; ++j) v += hist[tid * seg + j];

        // wave-level inclusive suffix scan: v = sum over lanes >= lane
#pragma unroll
        for (int d = 1; d < 64; d <<= 1) {
            unsigned int t = __shfl_down(v, (unsigned)d, 64);
            if (lane + d < 64) v += t;
        }
        if (lane == 0) waveTot[wave] = v;          // wave total
        __syncthreads();
        unsigned int basev = 0;
        for (int w = wave + 1; w < 16; ++w) basev += waveTot[w];
        unsigned int suf = v + basev;              // inclusive suffix over 1024
        sSuf[tid] = suf;
        __syncthreads();

        // unique boundary: largest tid with suffix >= R
        if (suf >= R && (tid == 1023 || sSuf[tid + 1] < R)) sTs = tid;
        __syncthreads();
        const int ts = sTs;

        if (tid == 0) {
            unsigned int cum = (ts < 1023) ? sSuf[ts + 1] : 0u;  // strictly above segment
            int sel = ts * seg;
            for (int bin = ts * seg + seg - 1; bin >= ts * seg; --bin) {
                unsigned int c = hist[bin];
                if (cum + c >= R) { sel = bin; break; }
                cum += c;
            }
            sPrefix = prefix | ((unsigned int)sel << shift);
            sR = R - cum;
        }
        __syncthreads();
        prefix = sPrefix;
        R = sR;
        __syncthreads();
    }

    const unsigned int T = prefix;  // exact Kth-largest key
    const unsigned int need = R;    // how many ==T to take (smallest indices first)

    // per-thread counts over a contiguous chunk, packed (GT<<16 | EQ).
    // Totals: GT < KSEL_=1638, EQ <= 16384 — both fit in 16 bits.
    const int CHUNK = N_ / 1024; // 16
    const int base = tid * CHUNK;
    unsigned int cGT = 0, cEQ = 0;
    for (int i = 0; i < CHUNK / 4; ++i) {
        uint4 u4 = sk4[(base >> 2) + i];
        cGT += (u4.x > T) + (u4.y > T) + (u4.z > T) + (u4.w > T);
        cEQ += (u4.x == T) + (u4.y == T) + (u4.z == T) + (u4.w == T);
    }
    unsigned int packed = (cGT << 16) | cEQ;
    unsigned int pv = packed;
#pragma unroll
    for (int d = 1; d < 64; d <<= 1) {
        unsigned int t = __shfl_up(pv, (unsigned)d, 64);
        if (lane >= d) pv += t;
    }
    if (lane == 63) wTotG[wave] = pv;              // wave total
    __syncthreads();
    unsigned int pbase = 0;
    for (int w = 0; w < wave; ++w) pbase += wTotG[w];
    unsigned int excl = pbase + pv - packed;       // exclusive prefix
    unsigned int gt = excl >> 16;
    unsigned int eq = excl & 0xFFFFu;

    int* ob = out + b * KSEL_;
    for (int i = 0; i < CHUNK; ++i) {
        unsigned int u = sKeys[base + i];
        if (u > T) {
            unsigned int eqSel = (eq < need) ? eq : need;
            ob[gt + eqSel] = base + i;
            gt++;
        } else if (u == T) {
            if (eq < need) ob[gt + eq] = base + i;
            eq++;
        }
    }
}

extern "C" void kernel_launch(void* const* d_in, const int* in_sizes, int n_in,
                              void* d_out, int out_size, void* d_ws, size_t ws_size,
                              hipStream_t stream) {
    const float* x       = (const float*)d_in[0];   // [B, N, D]
    const float* Wk      = (const float*)d_in[1];   // [RANK, D]
    const float* queries = (const float*)d_in[2];   // [NUMQ, RANK]
    int* out = (int*)d_out;                         // [B, KSEL] int32

    float*        Wq    = (float*)d_ws;                                        // 32 KiB
    unsigned int* keys  = (unsigned int*)((char*)d_ws + 32 * 1024);            // 256 KiB
    unsigned int* ghist = (unsigned int*)((char*)d_ws + (32 + 256) * 1024);    // 32 KiB

    wq_kernel<<<(NUMQ_ * D_ + 255) / 256, 256, 0, stream>>>(Wk, queries, Wq, ghist);
    score_kernel<<<2048, 256, 0, stream>>>(x, Wq, keys, ghist);
    topk_kernel<<<B_, 1024, 0, stream>>>(keys, ghist, out);
}

// Round 2
// 376.777 us; speedup vs baseline: 1.6932x; 1.6932x over previous
//
#include <hip/hip_runtime.h>
#include <stdint.h>

#define B_ 4
#define N_ 16384
#define D_ 1024
#define RANK_ 16
#define NUMQ_ 8
#define KSEL_ 1638

// ---------------- Kernel 1: Wq = queries @ Wk  -> [NUMQ, D] ----------------
__global__ __launch_bounds__(256) void wq_kernel(const float* __restrict__ Wk,
                                                 const float* __restrict__ queries,
                                                 float* __restrict__ Wq) {
    int i = blockIdx.x * 256 + threadIdx.x;   // 0 .. NUMQ*D-1 (8192)
    if (i >= NUMQ_ * D_) return;
    int q = i >> 10;          // / D_
    int d = i & (D_ - 1);     // % D_
    float acc = 0.f;
#pragma unroll
    for (int r = 0; r < RANK_; ++r)
        acc += queries[q * RANK_ + r] * Wk[r * D_ + d];
    Wq[i] = acc;
}

// ------------- Kernel 2: keys[t] = radix_key( max_q ( x[t,:] . Wq[q,:] ) ) -------------
// One wave processes TOK=4 tokens per iteration. Wq staged in LDS (32 KiB).
// Reduction: folding multi-value butterfly — 13 shuffles/token.
// Identical memory path to the proven Round-0 kernel (plain float4 loads, no
// atomics); only change: emit the order-preserving uint32 radix key so topk
// skips the float->key transform.
#define TOK 4

#define FOLD(dst, a, b, bit, dist)                          \
    {                                                       \
        float _send = (bit) ? (a) : (b);                    \
        float _recv = __shfl_xor(_send, (dist), 64);        \
        (dst) = ((bit) ? (b) : (a)) + _recv;                \
    }

__global__ __launch_bounds__(256) void score_kernel(const float* __restrict__ x,
                                                    const float* __restrict__ Wq,
                                                    unsigned int* __restrict__ keys) {
    __shared__ float sWq[NUMQ_ * D_];   // 32 KiB
    for (int i = threadIdx.x; i < (NUMQ_ * D_) / 4; i += 256)
        ((float4*)sWq)[i] = ((const float4*)Wq)[i];
    __syncthreads();

    const int lane = threadIdx.x & 63;
    const int wave = threadIdx.x >> 6;
    const int gw = blockIdx.x * 4 + wave;
    const int numWaves = gridDim.x * 4;
    const int totalTok = B_ * N_;

    const int l5 = (lane >> 5) & 1;
    const int l4 = (lane >> 4) & 1;
    const int l3 = (lane >> 3) & 1;

    for (int t0 = gw * TOK; t0 < totalTok; t0 += numWaves * TOK) {
        float acc[TOK][NUMQ_];
#pragma unroll
        for (int t = 0; t < TOK; ++t)
#pragma unroll
            for (int q = 0; q < NUMQ_; ++q) acc[t][q] = 0.f;

#pragma unroll
        for (int j = 0; j < 4; ++j) {
            const int off = j * 256 + lane * 4;   // lane-coalesced float4
            float4 xv[TOK];
#pragma unroll
            for (int t = 0; t < TOK; ++t)
                xv[t] = *(const float4*)(x + (size_t)(t0 + t) * D_ + off);
#pragma unroll
            for (int q = 0; q < NUMQ_; ++q) {
                float4 w = *(const float4*)(sWq + q * D_ + off);
#pragma unroll
                for (int t = 0; t < TOK; ++t) {
                    acc[t][q] += xv[t].x * w.x;
                    acc[t][q] += xv[t].y * w.y;
                    acc[t][q] += xv[t].z * w.z;
                    acc[t][q] += xv[t].w * w.w;
                }
            }
        }

#pragma unroll
        for (int t = 0; t < TOK; ++t) {
            float n0, n1, n2, n3;
            FOLD(n0, acc[t][0], acc[t][4], l5, 32)
            FOLD(n1, acc[t][1], acc[t][5], l5, 32)
            FOLD(n2, acc[t][2], acc[t][6], l5, 32)
            FOLD(n3, acc[t][3], acc[t][7], l5, 32)
            float m0, m1;
            FOLD(m0, n0, n2, l4, 16)
            FOLD(m1, n1, n3, l4, 16)
            float p;
            FOLD(p, m0, m1, l3, 8)
            p += __shfl_xor(p, 4, 64);
            p += __shfl_xor(p, 2, 64);
            p += __shfl_xor(p, 1, 64);
            float mx = p;
            mx = fmaxf(mx, __shfl_xor(mx, 8, 64));
            mx = fmaxf(mx, __shfl_xor(mx, 16, 64));
            mx = fmaxf(mx, __shfl_xor(mx, 32, 64));
            if (lane == t) {   // 4 contiguous words from lanes 0..3 -> one coalesced store
                unsigned int u = __float_as_uint(mx);
                u = (u & 0x80000000u) ? ~u : (u | 0x80000000u);
                keys[t0 + t] = u;
            }
        }
    }
}

// ------------- Kernel 3: per-batch top-K indices, sorted ascending -------------
// Radix-select 11/11/10 bits over precomputed uint32 keys. 1024 threads/block
// (16 waves); uint4-vectorized staging, histogram and count passes. Pass-0
// histogram built in-LDS (per-block contention only — proven cheap in R0).
__global__ __launch_bounds__(1024) void topk_kernel(const unsigned int* __restrict__ keys,
                                                    int* __restrict__ out) {
    __shared__ __align__(16) unsigned int sKeys[N_];   // 64 KiB
    __shared__ unsigned int hist[2048];                // 8 KiB
    __shared__ unsigned int sSuf[1024];                // 4 KiB
    __shared__ unsigned int waveTot[16];
    __shared__ unsigned int wTotG[16];
    __shared__ int sTs;
    __shared__ unsigned int sPrefix, sR;

    const int b = blockIdx.x;
    const int tid = threadIdx.x;
    const int lane = tid & 63;
    const int wave = tid >> 6;

    // vectorized stage of pre-transformed keys
    const uint4* kv = (const uint4*)(keys + b * N_);
    uint4* sk4 = (uint4*)sKeys;
    for (int i = tid; i < N_ / 4; i += 1024) sk4[i] = kv[i];
    __syncthreads();

    unsigned int prefix = 0;
    unsigned int R = KSEL_;   // rank from the top within the current prefix class

    const int shifts[3] = {21, 10, 0};
    const int widths[3] = {11, 11, 10};

#pragma unroll 1
    for (int pass = 0; pass < 3; ++pass) {
        const int shift = shifts[pass];
        const unsigned int nb = 1u << widths[pass];
        const unsigned int binmask = nb - 1u;
        const unsigned int maskHi = (pass == 0) ? 0u
                                  : (0xFFFFFFFFu << (shift + widths[pass]));

        for (int i = tid; i < (int)nb; i += 1024) hist[i] = 0;
        __syncthreads();
        for (int i = tid; i < N_ / 4; i += 1024) {
            uint4 u4 = sk4[i];
            unsigned int us[4] = {u4.x, u4.y, u4.z, u4.w};
#pragma unroll
            for (int c = 0; c < 4; ++c) {
                unsigned int u = us[c];
                if ((u & maskHi) == prefix)
                    atomicAdd(&hist[(u >> shift) & binmask], 1u);
            }
        }
        __syncthreads();

        // per-thread segment sum (seg consecutive bins), then suffix scan
        const int seg = (int)(nb >> 10);           // nb/1024: 2,2,1
        unsigned int v = 0;
        for (int j = 0; j < seg; ++j) v += hist[tid * seg + j];

        // wave-level inclusive suffix scan: v = sum over lanes >= lane
#pragma unroll
        for (int d = 1; d < 64; d <<= 1) {
            unsigned int t = __shfl_down(v, (unsigned)d, 64);
            if (lane + d < 64) v += t;
        }
        if (lane == 0) waveTot[wave] = v;          // wave total
        __syncthreads();
        unsigned int basev = 0;
        for (int w = wave + 1; w < 16; ++w) basev += waveTot[w];
        unsigned int suf = v + basev;              // inclusive suffix over 1024
        sSuf[tid] = suf;
        __syncthreads();

        // unique boundary: largest tid with suffix >= R
        if (suf >= R && (tid == 1023 || sSuf[tid + 1] < R)) sTs = tid;
        __syncthreads();
        const int ts = sTs;

        if (tid == 0) {
            unsigned int cum = (ts < 1023) ? sSuf[ts + 1] : 0u;  // strictly above segment
            int sel = ts * seg;
            for (int bin = ts * seg + seg - 1; bin >= ts * seg; --bin) {
                unsigned int c = hist[bin];
                if (cum + c >= R) { sel = bin; break; }
                cum += c;
            }
            sPrefix = prefix | ((unsigned int)sel << shift);
            sR = R - cum;
        }
        __syncthreads();
        prefix = sPrefix;
        R = sR;
        __syncthreads();
    }

    const unsigned int T = prefix;  // exact Kth-largest key
    const unsigned int need = R;    // how many ==T to take (smallest indices first)

    // per-thread counts over a contiguous chunk, packed (GT<<16 | EQ).
    // Totals: GT < KSEL_=1638, EQ <= 16384 — both fit in 16 bits.
    const int CHUNK = N_ / 1024; // 16
    const int base = tid * CHUNK;
    unsigned int cGT = 0, cEQ = 0;
    for (int i = 0; i < CHUNK / 4; ++i) {
        uint4 u4 = sk4[(base >> 2) + i];
        cGT += (u4.x > T) + (u4.y > T) + (u4.z > T) + (u4.w > T);
        cEQ += (u4.x == T) + (u4.y == T) + (u4.z == T) + (u4.w == T);
    }
    unsigned int packed = (cGT << 16) | cEQ;
    unsigned int pv = packed;
#pragma unroll
    for (int d = 1; d < 64; d <<= 1) {
        unsigned int t = __shfl_up(pv, (unsigned)d, 64);
        if (lane >= d) pv += t;
    }
    if (lane == 63) wTotG[wave] = pv;              // wave total
    __syncthreads();
    unsigned int pbase = 0;
    for (int w = 0; w < wave; ++w) pbase += wTotG[w];
    unsigned int excl = pbase + pv - packed;       // exclusive prefix
    unsigned int gt = excl >> 16;
    unsigned int eq = excl & 0xFFFFu;

    int* ob = out + b * KSEL_;
    for (int i = 0; i < CHUNK; ++i) {
        unsigned int u = sKeys[base + i];
        if (u > T) {
            unsigned int eqSel = (eq < need) ? eq : need;
            ob[gt + eqSel] = base + i;
            gt++;
        } else if (u == T) {
            if (eq < need) ob[gt + eq] = base + i;
            eq++;
        }
    }
}

extern "C" void kernel_launch(void* const* d_in, const int* in_sizes, int n_in,
                              void* d_out, int out_size, void* d_ws, size_t ws_size,
                              hipStream_t stream) {
    const float* x       = (const float*)d_in[0];   // [B, N, D]
    const float* Wk      = (const float*)d_in[1];   // [RANK, D]
    const float* queries = (const float*)d_in[2];   // [NUMQ, RANK]
    int* out = (int*)d_out;                         // [B, KSEL] int32

    float*        Wq   = (float*)d_ws;                              // 32 KiB
    unsigned int* keys = (unsigned int*)((char*)d_ws + 32 * 1024);  // 256 KiB

    wq_kernel<<<(NUMQ_ * D_ + 255) / 256, 256, 0, stream>>>(Wk, queries, Wq);
    score_kernel<<<2048, 256, 0, stream>>>(x, Wq, keys);
    topk_kernel<<<B_, 1024, 0, stream>>>(keys, out);
}

// Round 3
// 374.994 us; speedup vs baseline: 1.7013x; 1.0048x over previous
//
#include <hip/hip_runtime.h>
#include <stdint.h>

#define B_ 4
#define N_ 16384
#define D_ 1024
#define RANK_ 16
#define NUMQ_ 8
#define KSEL_ 1638

// ------------- Kernel 1: keys[t] = radix_key( max_q ( x[t,:] . Wq[q,:] ) ) -------------
// Wq = queries @ Wk is computed in each block's prologue directly into LDS
// (r-outer loop: every Wk element read exactly once per block, coalesced
// float4; queries reads are wave-uniform -> scalar). This removes the
// separate wq kernel and its launch gap.
// Main loop: one wave processes TOK=4 tokens per iteration; folding
// multi-value butterfly reduction — 13 shuffles/token. Emits the
// order-preserving uint32 radix key so topk skips the float->key transform.
#define TOK 4

#define FOLD(dst, a, b, bit, dist)                          \
    {                                                       \
        float _send = (bit) ? (a) : (b);                    \
        float _recv = __shfl_xor(_send, (dist), 64);        \
        (dst) = ((bit) ? (b) : (a)) + _recv;                \
    }

__global__ __launch_bounds__(256) void score_kernel(const float* __restrict__ x,
                                                    const float* __restrict__ Wk,
                                                    const float* __restrict__ queries,
                                                    unsigned int* __restrict__ keys) {
    __shared__ float sWq[NUMQ_ * D_];   // 32 KiB

    // ---- prologue: per-block Wq = queries @ Wk -> LDS ----
    {
        const int d0 = threadIdx.x * 4;        // thread owns 4 columns
        float4 acc[NUMQ_];
#pragma unroll
        for (int q = 0; q < NUMQ_; ++q) acc[q] = make_float4(0.f, 0.f, 0.f, 0.f);
#pragma unroll
        for (int r = 0; r < RANK_; ++r) {
            float4 wk = *(const float4*)(Wk + r * D_ + d0);   // coalesced, once/block
#pragma unroll
            for (int q = 0; q < NUMQ_; ++q) {
                float qv = queries[q * RANK_ + r];            // wave-uniform -> s_load
                acc[q].x += qv * wk.x;
                acc[q].y += qv * wk.y;
                acc[q].z += qv * wk.z;
                acc[q].w += qv * wk.w;
            }
        }
#pragma unroll
        for (int q = 0; q < NUMQ_; ++q)
            *(float4*)(sWq + q * D_ + d0) = acc[q];
    }
    __syncthreads();

    const int lane = threadIdx.x & 63;
    const int wave = threadIdx.x >> 6;
    const int gw = blockIdx.x * 4 + wave;
    const int numWaves = gridDim.x * 4;
    const int totalTok = B_ * N_;

    const int l5 = (lane >> 5) & 1;
    const int l4 = (lane >> 4) & 1;
    const int l3 = (lane >> 3) & 1;

    for (int t0 = gw * TOK; t0 < totalTok; t0 += numWaves * TOK) {
        float acc[TOK][NUMQ_];
#pragma unroll
        for (int t = 0; t < TOK; ++t)
#pragma unroll
            for (int q = 0; q < NUMQ_; ++q) acc[t][q] = 0.f;

#pragma unroll
        for (int j = 0; j < 4; ++j) {
            const int off = j * 256 + lane * 4;   // lane-coalesced float4
            float4 xv[TOK];
#pragma unroll
            for (int t = 0; t < TOK; ++t)
                xv[t] = *(const float4*)(x + (size_t)(t0 + t) * D_ + off);
#pragma unroll
            for (int q = 0; q < NUMQ_; ++q) {
                float4 w = *(const float4*)(sWq + q * D_ + off);
#pragma unroll
                for (int t = 0; t < TOK; ++t) {
                    acc[t][q] += xv[t].x * w.x;
                    acc[t][q] += xv[t].y * w.y;
                    acc[t][q] += xv[t].z * w.z;
                    acc[t][q] += xv[t].w * w.w;
                }
            }
        }

#pragma unroll
        for (int t = 0; t < TOK; ++t) {
            float n0, n1, n2, n3;
            FOLD(n0, acc[t][0], acc[t][4], l5, 32)
            FOLD(n1, acc[t][1], acc[t][5], l5, 32)
            FOLD(n2, acc[t][2], acc[t][6], l5, 32)
            FOLD(n3, acc[t][3], acc[t][7], l5, 32)
            float m0, m1;
            FOLD(m0, n0, n2, l4, 16)
            FOLD(m1, n1, n3, l4, 16)
            float p;
            FOLD(p, m0, m1, l3, 8)
            p += __shfl_xor(p, 4, 64);
            p += __shfl_xor(p, 2, 64);
            p += __shfl_xor(p, 1, 64);
            float mx = p;
            mx = fmaxf(mx, __shfl_xor(mx, 8, 64));
            mx = fmaxf(mx, __shfl_xor(mx, 16, 64));
            mx = fmaxf(mx, __shfl_xor(mx, 32, 64));
            if (lane == t) {   // 4 contiguous words from lanes 0..3 -> coalesced
                unsigned int u = __float_as_uint(mx);
                u = (u & 0x80000000u) ? ~u : (u | 0x80000000u);
                keys[t0 + t] = u;
            }
        }
    }
}

// ------------- Kernel 2: per-batch top-K indices, sorted ascending -------------
// Radix-select 11/11/10 bits over precomputed uint32 keys. 1024 threads/block
// (16 waves); uint4-vectorized staging, histogram and count passes. Pass-0
// histogram is built DURING key staging (saves one 16K LDS pass); LDS atomic
// contention is per-block only.
__global__ __launch_bounds__(1024) void topk_kernel(const unsigned int* __restrict__ keys,
                                                    int* __restrict__ out) {
    __shared__ __align__(16) unsigned int sKeys[N_];   // 64 KiB
    __shared__ unsigned int hist[2048];                // 8 KiB
    __shared__ unsigned int sSuf[1024];                // 4 KiB
    __shared__ unsigned int waveTot[16];
    __shared__ unsigned int wTotG[16];
    __shared__ int sTs;
    __shared__ unsigned int sPrefix, sR;

    const int b = blockIdx.x;
    const int tid = threadIdx.x;
    const int lane = tid & 63;
    const int wave = tid >> 6;

    for (int i = tid; i < 2048; i += 1024) hist[i] = 0;
    __syncthreads();

    // stage keys + build pass-0 (top 11 bits) histogram in one pass
    const uint4* kv = (const uint4*)(keys + b * N_);
    uint4* sk4 = (uint4*)sKeys;
    for (int i = tid; i < N_ / 4; i += 1024) {
        uint4 u4 = kv[i];
        sk4[i] = u4;
        atomicAdd(&hist[u4.x >> 21], 1u);
        atomicAdd(&hist[u4.y >> 21], 1u);
        atomicAdd(&hist[u4.z >> 21], 1u);
        atomicAdd(&hist[u4.w >> 21], 1u);
    }
    __syncthreads();

    unsigned int prefix = 0;
    unsigned int R = KSEL_;   // rank from the top within the current prefix class

    const int shifts[3] = {21, 10, 0};
    const int widths[3] = {11, 11, 10};

#pragma unroll 1
    for (int pass = 0; pass < 3; ++pass) {
        const int shift = shifts[pass];
        const unsigned int nb = 1u << widths[pass];
        const unsigned int binmask = nb - 1u;

        if (pass > 0) {   // pass-0 histogram was built during staging
            const unsigned int maskHi = 0xFFFFFFFFu << (shift + widths[pass]);
            for (int i = tid; i < (int)nb; i += 1024) hist[i] = 0;
            __syncthreads();
            for (int i = tid; i < N_ / 4; i += 1024) {
                uint4 u4 = sk4[i];
                unsigned int us[4] = {u4.x, u4.y, u4.z, u4.w};
#pragma unroll
                for (int c = 0; c < 4; ++c) {
                    unsigned int u = us[c];
                    if ((u & maskHi) == prefix)
                        atomicAdd(&hist[(u >> shift) & binmask], 1u);
                }
            }
            __syncthreads();
        }

        // per-thread segment sum (seg consecutive bins), then suffix scan
        const int seg = (int)(nb >> 10);           // nb/1024: 2,2,1
        unsigned int v = 0;
        for (int j = 0; j < seg; ++j) v += hist[tid * seg + j];

        // wave-level inclusive suffix scan: v = sum over lanes >= lane
#pragma unroll
        for (int d = 1; d < 64; d <<= 1) {
            unsigned int t = __shfl_down(v, (unsigned)d, 64);
            if (lane + d < 64) v += t;
        }
        if (lane == 0) waveTot[wave] = v;          // wave total
        __syncthreads();
        unsigned int basev = 0;
        for (int w = wave + 1; w < 16; ++w) basev += waveTot[w];
        unsigned int suf = v + basev;              // inclusive suffix over 1024
        sSuf[tid] = suf;
        __syncthreads();

        // unique boundary: largest tid with suffix >= R
        if (suf >= R && (tid == 1023 || sSuf[tid + 1] < R)) sTs = tid;
        __syncthreads();
        const int ts = sTs;

        if (tid == 0) {
            unsigned int cum = (ts < 1023) ? sSuf[ts + 1] : 0u;  // strictly above segment
            int sel = ts * seg;
            for (int bin = ts * seg + seg - 1; bin >= ts * seg; --bin) {
                unsigned int c = hist[bin];
                if (cum + c >= R) { sel = bin; break; }
                cum += c;
            }
            sPrefix = prefix | ((unsigned int)sel << shift);
            sR = R - cum;
        }
        __syncthreads();
        prefix = sPrefix;
        R = sR;
        __syncthreads();
    }

    const unsigned int T = prefix;  // exact Kth-largest key
    const unsigned int need = R;    // how many ==T to take (smallest indices first)

    // per-thread counts over a contiguous chunk, packed (GT<<16 | EQ).
    // Totals: GT < KSEL_=1638, EQ <= 16384 — both fit in 16 bits.
    const int CHUNK = N_ / 1024; // 16
    const int base = tid * CHUNK;
    unsigned int cGT = 0, cEQ = 0;
    for (int i = 0; i < CHUNK / 4; ++i) {
        uint4 u4 = sk4[(base >> 2) + i];
        cGT += (u4.x > T) + (u4.y > T) + (u4.z > T) + (u4.w > T);
        cEQ += (u4.x == T) + (u4.y == T) + (u4.z == T) + (u4.w == T);
    }
    unsigned int packed = (cGT << 16) | cEQ;
    unsigned int pv = packed;
#pragma unroll
    for (int d = 1; d < 64; d <<= 1) {
        unsigned int t = __shfl_up(pv, (unsigned)d, 64);
        if (lane >= d) pv += t;
    }
    if (lane == 63) wTotG[wave] = pv;              // wave total
    __syncthreads();
    unsigned int pbase = 0;
    for (int w = 0; w < wave; ++w) pbase += wTotG[w];
    unsigned int excl = pbase + pv - packed;       // exclusive prefix
    unsigned int gt = excl >> 16;
    unsigned int eq = excl & 0xFFFFu;

    int* ob = out + b * KSEL_;
    for (int i = 0; i < CHUNK; ++i) {
        unsigned int u = sKeys[base + i];
        if (u > T) {
            unsigned int eqSel = (eq < need) ? eq : need;
            ob[gt + eqSel] = base + i;
            gt++;
        } else if (u == T) {
            if (eq < need) ob[gt + eq] = base + i;
            eq++;
        }
    }
}

extern "C" void kernel_launch(void* const* d_in, const int* in_sizes, int n_in,
                              void* d_out, int out_size, void* d_ws, size_t ws_size,
                              hipStream_t stream) {
    const float* x       = (const float*)d_in[0];   // [B, N, D]
    const float* Wk      = (const float*)d_in[1];   // [RANK, D]
    const float* queries = (const float*)d_in[2];   // [NUMQ, RANK]
    int* out = (int*)d_out;                         // [B, KSEL] int32

    unsigned int* keys = (unsigned int*)d_ws;       // 256 KiB

    // 1024 blocks = one co-resident generation (4 blocks/CU x 256 CU);
    // every wave handles exactly 16 tokens.
    score_kernel<<<1024, 256, 0, stream>>>(x, Wk, queries, keys);
    topk_kernel<<<B_, 1024, 0, stream>>>(keys, out);
}